// Round 15
// baseline (383.666 us; speedup 1.0000x reference)
//
#include <hip/hip_runtime.h>
#include <hip/hip_bf16.h>
#include <stdint.h>

#define NN 10000
#define NE 250000
#define FEAT 16
#define EMB 32
#define HID 32
#define NV 12
#define EAD 9
#define NG 64

// ---------------------------------------------------------------------------
// dst in-degree histogram
// ---------------------------------------------------------------------------
__global__ void edge_stats_kernel(const int* __restrict__ dst,
                                  int* __restrict__ histD) {
    int e = blockIdx.x * blockDim.x + threadIdx.x;
    if (e >= NE) return;
    atomicAdd(&histD[dst[e]], 1);
}

// ---------------------------------------------------------------------------
// Single-block exclusive scan: histD[NN] -> rowD[NN+1], curD[NN]
// ---------------------------------------------------------------------------
__global__ __launch_bounds__(1024) void scan_kernel(const int* __restrict__ hist,
                                                    int* __restrict__ rowStart,
                                                    int* __restrict__ cursor) {
    __shared__ int part[1024];
    int t = threadIdx.x;
    int base = t * 10;
    int local[10];
    int s = 0;
#pragma unroll
    for (int i = 0; i < 10; ++i) {
        int v = (base + i < NN) ? hist[base + i] : 0;
        local[i] = s;
        s += v;
    }
    part[t] = s;
    __syncthreads();
    for (int off = 1; off < 1024; off <<= 1) {
        int v = (t >= off) ? part[t - off] : 0;
        __syncthreads();
        part[t] += v;
        __syncthreads();
    }
    int pre = (t == 0) ? 0 : part[t - 1];
#pragma unroll
    for (int i = 0; i < 10; ++i) {
        if (base + i < NN) {
            int rs = pre + local[i];
            rowStart[base + i] = rs;
            cursor[base + i] = rs;
        }
    }
    if (t == 1023) rowStart[NN] = part[1023];
}

// ---------------------------------------------------------------------------
// Permute edges to DST-sorted order (ea padded to 12 floats); record src id.
// ---------------------------------------------------------------------------
__global__ void scatter_kernel(const float* __restrict__ ea,
                               const int* __restrict__ src,
                               const int* __restrict__ dst,
                               int* __restrict__ cursorD,
                               float* __restrict__ ea_d,   // [E,12] dst-sorted
                               int* __restrict__ src_d) {  // [E]
    int e = blockIdx.x * blockDim.x + threadIdx.x;
    if (e >= NE) return;
    int dv = dst[e];
    int pos = atomicAdd(&cursorD[dv], 1);
    src_d[pos] = src[e];
#pragma unroll
    for (int j = 0; j < 12; ++j)
        ea_d[(size_t)pos * 12 + j] = (j < EAD) ? ea[(size_t)e * EAD + j] : 0.f;
}

// ---------------------------------------------------------------------------
// Fully fused NNConv: persistent blocks (4 waves); W2eq staged once per block
// in LDS transposed [o][f] (+1 pad row); wave = one dst node:
//   edge loop: edge-MLP (lane k -> hidden[k], shared via per-wave LDS),
//     gather h[src] (lane's column), accumulate moments C[f]=sum hid[k]*h[i]
//     distributed f == lane (mod 64) in registers (k==32 slot: hid==1 -> sbar).
//   write C to wave-private LDS; lane o: msum = sum_{f in half} C[f]*W[o][f];
//   shfl_xor(32) fold; epilogue: mean + root + bias + ReLU + store / pool.
// No large intermediates, no global atomics (except tiny pooled).
// ---------------------------------------------------------------------------
template <int DIN, bool POOL>
__global__ __launch_bounds__(256) void fused_conv_kernel(
    const float* __restrict__ ea_d,   // [E,12] dst-sorted
    const int* __restrict__ src_d,    // [E]
    const int* __restrict__ rowD,     // [N+1]
    const float* __restrict__ w1,     // [9,32]
    const float* __restrict__ b1,     // [32]
    const float* __restrict__ w2,     // [32, DIN*32]
    const float* __restrict__ b2,     // [DIN*32]
    const float* __restrict__ h,      // [N,DIN]
    const float* __restrict__ root,   // [DIN,32]
    const float* __restrict__ bias,   // [32]
    float* __restrict__ hout,         // [N,32] (non-POOL)
    float* __restrict__ pooled,       // [G,32] (POOL)
    const int* __restrict__ batch,
    float* __restrict__ gcnt)         // [G]
{
    constexpr int K = 33 * DIN;          // 528 / 1056
    constexpr int WST = K + 1;           // pad row -> bank (o+f)&31
    constexpr int NSLOT = (K + 63) / 64; // 9 / 17
    constexpr int KH = K / 2;

    extern __shared__ float smem[];
    float* sW    = smem;                    // 32*WST
    float* sroot = sW + 32 * WST;           // DIN*32
    float* sC    = sroot + DIN * 32;        // 4*K  (wave-private)
    float* shid  = sC + 4 * K;              // 4*32 (+pad after)

    int t = threadIdx.x;
    // ---- stage W2eq transposed + root (once per block) ----
    for (int idx = t; idx < K * 32; idx += 256) {
        int f = idx >> 5, o = idx & 31;
        int k = f / DIN, i = f % DIN;
        float v = (k < 32) ? w2[(size_t)k * (DIN * 32) + i * 32 + o]
                           : b2[i * 32 + o];
        sW[o * WST + f] = v;
    }
    for (int idx = t; idx < DIN * 32; idx += 256) sroot[idx] = root[idx];
    __syncthreads();

    int wv = t >> 6;
    int l = t & 63;
    int o = l & 31;
    int half = l >> 5;
    int ihl = l & (DIN - 1);
    float* myhid = shid + wv * 32;
    float* myC = sC + wv * K;

    float w1r[EAD];
#pragma unroll
    for (int j = 0; j < EAD; ++j) w1r[j] = w1[j * 32 + o];
    float b1r = b1[o];
    float bo = bias[o];

    int nwaves = gridDim.x * 4;
    for (int n = blockIdx.x * 4 + wv; n < NN; n += nwaves) {
        int beg = rowD[n], end = rowD[n + 1];
        int deg = end - beg;

        float c[NSLOT];
#pragma unroll
        for (int j = 0; j < NSLOT; ++j) c[j] = 0.f;

        for (int e = beg; e < end; ++e) {
            const float4* eav = (const float4*)(ea_d + (size_t)e * 12);
            float4 a0 = eav[0], a1 = eav[1], a2 = eav[2];
            float hs = b1r
                + a0.x * w1r[0] + a0.y * w1r[1] + a0.z * w1r[2] + a0.w * w1r[3]
                + a1.x * w1r[4] + a1.y * w1r[5] + a1.z * w1r[6] + a1.w * w1r[7]
                + a2.x * w1r[8];
            float hd = fmaxf(hs, 0.f);
            if (l < 32) myhid[o] = hd;
            __builtin_amdgcn_wave_barrier();

            int sv = src_d[e];
            float hval = h[(size_t)sv * DIN + ihl];
#pragma unroll
            for (int j = 0; j < NSLOT; ++j) {
                int f = 64 * j + l;
                if (f < K) {
                    int kj = (64 * j) / DIN + (DIN == 32 ? (l >> 5) : (l >> 4));
                    float hm = (kj == 32) ? 1.0f : myhid[kj];
                    c[j] += hm * hval;
                }
            }
            __builtin_amdgcn_wave_barrier();
        }

        // ---- C to wave-private LDS ----
#pragma unroll
        for (int j = 0; j < NSLOT; ++j) {
            int f = 64 * j + l;
            if (f < K) myC[f] = c[j];
        }
        __builtin_amdgcn_wave_barrier();

        // ---- GEMM: lane o over its f-half ----
        const float* wrow = sW + (size_t)o * WST + half * KH;
        const float* crow = myC + half * KH;
        float msum = 0.f;
#pragma unroll 4
        for (int fh = 0; fh < KH; fh += 4) {
            float4 cv = *(const float4*)(crow + fh);
            msum += cv.x * wrow[fh] + cv.y * wrow[fh + 1]
                  + cv.z * wrow[fh + 2] + cv.w * wrow[fh + 3];
        }
        msum += __shfl_xor(msum, 32);
        __builtin_amdgcn_wave_barrier();

        // ---- epilogue ----
        float v = msum / fmaxf((float)deg, 1.0f) + bo;
        const float* hrow = h + (size_t)n * DIN;
#pragma unroll
        for (int i = 0; i < DIN; ++i) v += hrow[i] * sroot[i * 32 + o];
        v = fmaxf(v, 0.f);
        if (l < 32) {
            if (!POOL) {
                hout[(size_t)n * 32 + o] = v;
            } else {
                int g = batch[n];
                atomicAdd(&pooled[g * 32 + o], v);
                if (o == 0) atomicAdd(&gcnt[g], 1.0f);
            }
        }
    }
}

// ---------------------------------------------------------------------------
// pooled mean -> linear(32,12) -> log_softmax
// ---------------------------------------------------------------------------
__global__ void final_kernel(const float* __restrict__ pooled,
                             const float* __restrict__ gcnt,
                             const float* __restrict__ lin_w,
                             const float* __restrict__ lin_b,
                             float* __restrict__ out) {
    int g = threadIdx.x;
    if (g >= NG) return;
    float inv = 1.0f / fmaxf(gcnt[g], 1.0f);
    float p[HID];
#pragma unroll
    for (int h = 0; h < HID; ++h) p[h] = pooled[g * HID + h] * inv;
    float logits[NV];
    float mx = -1e30f;
#pragma unroll
    for (int v = 0; v < NV; ++v) {
        float s = lin_b[v];
#pragma unroll
        for (int h = 0; h < HID; ++h) s += p[h] * lin_w[h * NV + v];
        logits[v] = s;
        mx = fmaxf(mx, s);
    }
    float se = 0.f;
#pragma unroll
    for (int v = 0; v < NV; ++v) se += expf(logits[v] - mx);
    float lse = mx + logf(se);
#pragma unroll
    for (int v = 0; v < NV; ++v) out[g * NV + v] = logits[v] - lse;
}

// ---------------------------------------------------------------------------
extern "C" void kernel_launch(void* const* d_in, const int* in_sizes, int n_in,
                              void* d_out, int out_size, void* d_ws, size_t ws_size,
                              hipStream_t stream) {
    const float* x        = (const float*)d_in[0];
    const float* ea       = (const float*)d_in[1];
    const int*   eidx     = (const int*)d_in[2];
    const int*   batch    = (const int*)d_in[3];
    const float* nn1_w1   = (const float*)d_in[4];
    const float* nn1_b1   = (const float*)d_in[5];
    const float* nn1_w2   = (const float*)d_in[6];
    const float* nn1_b2   = (const float*)d_in[7];
    const float* root1    = (const float*)d_in[8];
    const float* bias1    = (const float*)d_in[9];
    const float* nn2_w1   = (const float*)d_in[10];
    const float* nn2_b1   = (const float*)d_in[11];
    const float* nn2_w2   = (const float*)d_in[12];
    const float* nn2_b2   = (const float*)d_in[13];
    const float* root2    = (const float*)d_in[14];
    const float* bias2    = (const float*)d_in[15];
    const float* lin_w    = (const float*)d_in[16];
    const float* lin_b    = (const float*)d_in[17];
    float* out = (float*)d_out;

    const int* src = eidx;
    const int* dst = eidx + NE;

    // workspace
    char* base = (char*)d_ws;
    float* ea_d   = (float*)base;                           // NE*12
    float* h1     = ea_d + (size_t)NE * 12;                 // NN*32
    int*   src_d  = (int*)(h1 + (size_t)NN * 32);           // NE
    int*   rowD   = src_d + NE;                             // NN+1
    int*   curD   = rowD + NN + 1;                          // NN
    int*   histD  = curD + NN;                              // NN (zeroed from here)
    float* pooled = (float*)(histD + NN);                   // NG*32
    float* gcnt   = pooled + NG * 32;                       // NG
    size_t zero_bytes = ((size_t)NN + NG * 32 + NG) * 4;

    hipMemsetAsync(histD, 0, zero_bytes, stream);

    // ---- dst-sort pre-pass ----
    edge_stats_kernel<<<(NE + 255) / 256, 256, 0, stream>>>(dst, histD);
    scan_kernel<<<1, 1024, 0, stream>>>(histD, rowD, curD);
    scatter_kernel<<<(NE + 255) / 256, 256, 0, stream>>>(ea, src, dst, curD,
                                                         ea_d, src_d);

    // dynamic LDS sizes (+128B pad for the kj==32 speculative read)
    const int smem1 = 32 * (33 * FEAT + 1) * 4 + FEAT * 32 * 4
                    + 4 * 33 * FEAT * 4 + 4 * 32 * 4 + 128;   // ~78.8 KB
    const int smem2 = 32 * (33 * EMB + 1) * 4 + EMB * 32 * 4
                    + 4 * 33 * EMB * 4 + 4 * 32 * 4 + 128;    // ~156.9 KB

    auto* k1 = fused_conv_kernel<FEAT, false>;
    auto* k2 = fused_conv_kernel<EMB, true>;
    hipFuncSetAttribute((const void*)k1,
                        hipFuncAttributeMaxDynamicSharedMemorySize, smem1);
    hipFuncSetAttribute((const void*)k2,
                        hipFuncAttributeMaxDynamicSharedMemorySize, smem2);

    // ---- conv1: x -> h1 ----
    k1<<<512, 256, smem1, stream>>>(
        ea_d, src_d, rowD, nn1_w1, nn1_b1, nn1_w2, nn1_b2,
        x, root1, bias1, h1, nullptr, nullptr, nullptr);

    // ---- conv2: h1 -> pooled ----
    k2<<<256, 256, smem2, stream>>>(
        ea_d, src_d, rowD, nn2_w1, nn2_b1, nn2_w2, nn2_b2,
        h1, root2, bias2, nullptr, pooled, batch, gcnt);

    // ---- head ----
    final_kernel<<<1, 64, 0, stream>>>(pooled, gcnt, lin_w, lin_b, out);
}

// Round 16
// 260.088 us; speedup vs baseline: 1.4751x; 1.4751x over previous
//
#include <hip/hip_runtime.h>
#include <hip/hip_bf16.h>
#include <stdint.h>

#define NN 10000
#define NE 250000
#define FEAT 16
#define EMB 32
#define HID 32
#define NV 12
#define EAD 9
#define NG 64
#define EPB 128   // edges per block in edge_agg
#define NCH 25    // nodes per block in computeQ-shaped kernels

__device__ __forceinline__ uint32_t bf16rne(float f) {
    uint32_t u = __float_as_uint(f);
    return (u + 0x7fffu + ((u >> 16) & 1u)) >> 16;
}
__device__ __forceinline__ float blo(uint32_t p) { return __uint_as_float(p << 16); }
__device__ __forceinline__ float bhi(uint32_t p) { return __uint_as_float(p & 0xffff0000u); }

// ---------------------------------------------------------------------------
// src/dst degree histograms
// ---------------------------------------------------------------------------
__global__ void edge_stats_kernel(const int* __restrict__ src,
                                  const int* __restrict__ dst,
                                  int* __restrict__ histS,
                                  int* __restrict__ histD) {
    int e = blockIdx.x * blockDim.x + threadIdx.x;
    if (e >= NE) return;
    atomicAdd(&histS[src[e]], 1);
    atomicAdd(&histD[dst[e]], 1);
}

// ---------------------------------------------------------------------------
// Single-block exclusive scan of histS[NN] -> rowS[NN+1], curS[NN]
// ---------------------------------------------------------------------------
__global__ __launch_bounds__(1024) void scan_kernel(const int* __restrict__ hist,
                                                    int* __restrict__ rowStart,
                                                    int* __restrict__ cursor) {
    __shared__ int part[1024];
    int t = threadIdx.x;
    int base = t * 10;
    int local[10];
    int s = 0;
#pragma unroll
    for (int i = 0; i < 10; ++i) {
        int v = (base + i < NN) ? hist[base + i] : 0;
        local[i] = s;
        s += v;
    }
    part[t] = s;
    __syncthreads();
    for (int off = 1; off < 1024; off <<= 1) {
        int v = (t >= off) ? part[t - off] : 0;
        __syncthreads();
        part[t] += v;
        __syncthreads();
    }
    int pre = (t == 0) ? 0 : part[t - 1];
#pragma unroll
    for (int i = 0; i < 10; ++i) {
        if (base + i < NN) {
            int rs = pre + local[i];
            rowStart[base + i] = rs;
            cursor[base + i] = rs;
        }
    }
    if (t == 1023) rowStart[NN] = part[1023];
}

// ---------------------------------------------------------------------------
// Permute edges to src-sorted order (ea padded to 12 floats for float4 loads).
// ---------------------------------------------------------------------------
__global__ void scatter_kernel(const float* __restrict__ ea,
                               const int* __restrict__ src,
                               const int* __restrict__ dst,
                               int* __restrict__ cursorS,
                               float* __restrict__ ea_p,   // [E,12]
                               int* __restrict__ src_s,
                               int* __restrict__ dst_s) {
    int e = blockIdx.x * blockDim.x + threadIdx.x;
    if (e >= NE) return;
    int sv = src[e];
    int pos = atomicAdd(&cursorS[sv], 1);
    src_s[pos] = sv;
    dst_s[pos] = dst[e];
#pragma unroll
    for (int j = 0; j < 12; ++j)
        ea_p[(size_t)pos * 12 + j] = (j < EAD) ? ea[(size_t)e * EAD + j] : 0.f;
}

// ---------------------------------------------------------------------------
// Conv1 Q: Qp[n][kk][o] = packed bf16 pair of Q[n,2kk,o]/Q[n,2kk+1,o];
// kk==0 lanes also emit fp32 bias row Qb. (round-8 kernel, reads x)
// ---------------------------------------------------------------------------
template <int DIN>
__global__ __launch_bounds__(256) void computeQ_pack_kernel(
    const float* __restrict__ h,    // [N,DIN]
    const float* __restrict__ w2,   // [32, DIN*32]
    const float* __restrict__ b2,   // [DIN*32]
    uint32_t* __restrict__ Qp,      // [N,16,32]
    float* __restrict__ Qb)         // [N,32]
{
    int t = threadIdx.x;
    int o = t & 31;
    int kk = (blockIdx.y * 256 + t) >> 5;  // 0..15
    float w0[DIN], w1r[DIN];
    const float* wa = w2 + (size_t)(2 * kk) * (DIN * 32) + o;
    const float* wb = w2 + (size_t)(2 * kk + 1) * (DIN * 32) + o;
#pragma unroll
    for (int i = 0; i < DIN; ++i) { w0[i] = wa[i * 32]; w1r[i] = wb[i * 32]; }

    int n0 = blockIdx.x * NCH;
    for (int j = 0; j < NCH; ++j) {
        int n = n0 + j;
        const float* hn = h + (size_t)n * DIN;
        float s0 = 0.f, s1 = 0.f;
#pragma unroll
        for (int i = 0; i < DIN; ++i) {
            float hv = hn[i];
            s0 += hv * w0[i];
            s1 += hv * w1r[i];
        }
        Qp[((size_t)n * 16 + kk) * 32 + o] = (bf16rne(s1) << 16) | bf16rne(s0);
        if (kk == 0) {
            float sb = 0.f;
#pragma unroll
            for (int i = 0; i < DIN; ++i) sb += hn[i] * b2[i * 32 + o];
            Qb[(size_t)n * 32 + o] = sb;
        }
    }
}

// ---------------------------------------------------------------------------
// Fused node1 + conv2 Q: phase A computes h1 rows for the block's 25 nodes
// (h1 = relu(agg1/deg + x@root1 + bias1)) into LDS (y==0 also stores h1);
// phase B = standard register-w2 Q-pack for conv2 reading h1 from LDS.
// Replaces the node_update dispatch: agg reads are absorbed into a busy,
// 800-block compute kernel.
// ---------------------------------------------------------------------------
__global__ __launch_bounds__(256) void computeQ2h_kernel(
    const float* __restrict__ agg1,   // [N,32]
    const int* __restrict__ histD,    // [N]
    const float* __restrict__ x,      // [N,16]
    const float* __restrict__ root1,  // [16,32]
    const float* __restrict__ bias1,  // [32]
    const float* __restrict__ w2,     // nn2_w2 [32, 32*32]
    const float* __restrict__ b2,     // nn2_b2 [32*32]
    float* __restrict__ h1out,        // [N,32]
    uint32_t* __restrict__ Qp,        // [N,16,32]
    float* __restrict__ Qb)           // [N,32]
{
    __shared__ float s_x[NCH][17];
    __shared__ float s_root[16][32];
    __shared__ float s_h1[NCH][33];
    __shared__ float s_bias[32];
    __shared__ float s_deg[NCH];

    int t = threadIdx.x;
    int n0 = blockIdx.x * NCH;

    for (int idx = t; idx < NCH * 16; idx += 256) {
        int nl = idx >> 4, i = idx & 15;
        s_x[nl][i] = x[(size_t)(n0 + nl) * 16 + i];
    }
    for (int idx = t; idx < 16 * 32; idx += 256)
        s_root[idx >> 5][idx & 31] = root1[idx];
    if (t < 32) s_bias[t] = bias1[t];
    if (t < NCH) s_deg[t] = fmaxf((float)histD[n0 + t], 1.0f);
    __syncthreads();

    // ---- phase A: h1 rows (coalesced agg1 reads; busy FMA work) ----
    for (int idx = t; idx < NCH * 32; idx += 256) {
        int nl = idx >> 5, i = idx & 31;
        float v = agg1[(size_t)(n0 + nl) * 32 + i] / s_deg[nl] + s_bias[i];
#pragma unroll
        for (int j = 0; j < 16; ++j) v += s_x[nl][j] * s_root[j][i];
        v = fmaxf(v, 0.f);
        s_h1[nl][i] = v;
        if (blockIdx.y == 0) h1out[(size_t)(n0 + nl) * 32 + i] = v;
    }
    __syncthreads();

    // ---- phase B: conv2 Q-pack (DIN=32), h from LDS ----
    int o = t & 31;
    int kk = blockIdx.y * 8 + (t >> 5);    // 0..15
    float w0[32], w1r[32];
    const float* wa = w2 + (size_t)(2 * kk) * 1024 + o;
    const float* wb = w2 + (size_t)(2 * kk + 1) * 1024 + o;
#pragma unroll
    for (int i = 0; i < 32; ++i) { w0[i] = wa[i * 32]; w1r[i] = wb[i * 32]; }

    for (int j = 0; j < NCH; ++j) {
        float s0 = 0.f, s1 = 0.f;
#pragma unroll
        for (int i = 0; i < 32; ++i) {
            float hv = s_h1[j][i];
            s0 += hv * w0[i];
            s1 += hv * w1r[i];
        }
        Qp[((size_t)(n0 + j) * 16 + kk) * 32 + o] = (bf16rne(s1) << 16) | bf16rne(s0);
        if (kk == 0) {
            float sb = 0.f;
#pragma unroll
            for (int i = 0; i < 32; ++i) sb += s_h1[j][i] * b2[i * 32 + o];
            Qb[(size_t)(n0 + j) * 32 + o] = sb;
        }
    }
}

// ---------------------------------------------------------------------------
// Edge messages fused with scatter-add aggregation (round-8 kernel).
// ---------------------------------------------------------------------------
__global__ __launch_bounds__(256) void edge_agg_kernel(
    const float* __restrict__ ea_p,   // [E,12]
    const int* __restrict__ src_s,
    const int* __restrict__ dst_s,
    const float* __restrict__ w1,     // [9,32]
    const float* __restrict__ b1,     // [32]
    const uint32_t* __restrict__ Qp,  // [N,16,32]
    const float* __restrict__ Qb,     // [N,32]
    float* __restrict__ agg)          // [N,32]
{
    __shared__ float s_hid[8][32];
    int t = threadIdx.x;
    int o = t & 31;
    int slot = t >> 5;

    float w1r[EAD];
#pragma unroll
    for (int j = 0; j < EAD; ++j) w1r[j] = w1[j * 32 + o];
    float b1r = b1[o];

    int base = blockIdx.x * EPB;
    int eend = min(base + EPB, NE);
    for (int e = base + slot; e < eend; e += 8) {
        const float4* eav = (const float4*)(ea_p + (size_t)e * 12);
        float4 a0 = eav[0], a1 = eav[1], a2 = eav[2];
        float hs = b1r;
        hs += a0.x * w1r[0] + a0.y * w1r[1] + a0.z * w1r[2] + a0.w * w1r[3];
        hs += a1.x * w1r[4] + a1.y * w1r[5] + a1.z * w1r[6] + a1.w * w1r[7];
        hs += a2.x * w1r[8];
        float hd = fmaxf(hs, 0.f);

        s_hid[slot][o] = hd;
        __builtin_amdgcn_wave_barrier();

        int sv = src_s[e];
        const uint32_t* q = Qp + (size_t)sv * 512 + o;
        float m = Qb[(size_t)sv * 32 + o];
        const float4* hq = (const float4*)(&s_hid[slot][0]);
#pragma unroll
        for (int c = 0; c < 8; ++c) {
            float4 hv = hq[c];
            uint32_t qa  = q[(2 * c) * 32];
            uint32_t qb2 = q[(2 * c + 1) * 32];
            m += hv.x * blo(qa) + hv.y * bhi(qa)
               + hv.z * blo(qb2) + hv.w * bhi(qb2);
        }
        atomicAdd(&agg[(size_t)dst_s[e] * 32 + o], m);
        __builtin_amdgcn_wave_barrier();
    }
}

// ---------------------------------------------------------------------------
// Node2 + pooling, computeQ-shaped: block = 25 nodes; h2 = relu(agg2/deg +
// h1@root2 + bias2); atomicAdd into pooled/gcnt (tiny targets).
// ---------------------------------------------------------------------------
__global__ __launch_bounds__(256) void pool_kernel(
    const float* __restrict__ agg2,   // [N,32]
    const int* __restrict__ histD,    // [N]
    const float* __restrict__ h1,     // [N,32]
    const float* __restrict__ root2,  // [32,32]
    const float* __restrict__ bias2,  // [32]
    const int* __restrict__ batch,    // [N]
    float* __restrict__ pooled,       // [G,32]
    float* __restrict__ gcnt)         // [G]
{
    __shared__ float s_h1[NCH][33];
    __shared__ float s_root[32][33];
    __shared__ float s_bias[32];
    __shared__ float s_deg[NCH];
    __shared__ int s_batch[NCH];

    int t = threadIdx.x;
    int n0 = blockIdx.x * NCH;

    for (int idx = t; idx < NCH * 32; idx += 256) {
        int nl = idx >> 5, i = idx & 31;
        s_h1[nl][i] = h1[(size_t)(n0 + nl) * 32 + i];
    }
    for (int idx = t; idx < 32 * 32; idx += 256)
        s_root[idx >> 5][idx & 31] = root2[idx];
    if (t < 32) s_bias[t] = bias2[t];
    if (t < NCH) {
        s_deg[t] = fmaxf((float)histD[n0 + t], 1.0f);
        s_batch[t] = batch[n0 + t];
    }
    __syncthreads();

    for (int idx = t; idx < NCH * 32; idx += 256) {
        int nl = idx >> 5, o = idx & 31;
        float v = agg2[(size_t)(n0 + nl) * 32 + o] / s_deg[nl] + s_bias[o];
#pragma unroll
        for (int i = 0; i < 32; ++i) v += s_h1[nl][i] * s_root[i][o];
        v = fmaxf(v, 0.f);
        int g = s_batch[nl];
        atomicAdd(&pooled[g * 32 + o], v);
        if (o == 0) atomicAdd(&gcnt[g], 1.0f);
    }
}

// ---------------------------------------------------------------------------
// pooled mean -> linear(32,12) -> log_softmax
// ---------------------------------------------------------------------------
__global__ void final_kernel(const float* __restrict__ pooled,
                             const float* __restrict__ gcnt,
                             const float* __restrict__ lin_w,
                             const float* __restrict__ lin_b,
                             float* __restrict__ out) {
    int g = threadIdx.x;
    if (g >= NG) return;
    float inv = 1.0f / fmaxf(gcnt[g], 1.0f);
    float p[HID];
#pragma unroll
    for (int h = 0; h < HID; ++h) p[h] = pooled[g * HID + h] * inv;
    float logits[NV];
    float mx = -1e30f;
#pragma unroll
    for (int v = 0; v < NV; ++v) {
        float s = lin_b[v];
#pragma unroll
        for (int h = 0; h < HID; ++h) s += p[h] * lin_w[h * NV + v];
        logits[v] = s;
        mx = fmaxf(mx, s);
    }
    float se = 0.f;
#pragma unroll
    for (int v = 0; v < NV; ++v) se += expf(logits[v] - mx);
    float lse = mx + logf(se);
#pragma unroll
    for (int v = 0; v < NV; ++v) out[g * NV + v] = logits[v] - lse;
}

// ---------------------------------------------------------------------------
extern "C" void kernel_launch(void* const* d_in, const int* in_sizes, int n_in,
                              void* d_out, int out_size, void* d_ws, size_t ws_size,
                              hipStream_t stream) {
    const float* x        = (const float*)d_in[0];
    const float* ea       = (const float*)d_in[1];
    const int*   eidx     = (const int*)d_in[2];
    const int*   batch    = (const int*)d_in[3];
    const float* nn1_w1   = (const float*)d_in[4];
    const float* nn1_b1   = (const float*)d_in[5];
    const float* nn1_w2   = (const float*)d_in[6];
    const float* nn1_b2   = (const float*)d_in[7];
    const float* root1    = (const float*)d_in[8];
    const float* bias1    = (const float*)d_in[9];
    const float* nn2_w1   = (const float*)d_in[10];
    const float* nn2_b1   = (const float*)d_in[11];
    const float* nn2_w2   = (const float*)d_in[12];
    const float* nn2_b2   = (const float*)d_in[13];
    const float* root2    = (const float*)d_in[14];
    const float* bias2    = (const float*)d_in[15];
    const float* lin_w    = (const float*)d_in[16];
    const float* lin_b    = (const float*)d_in[17];
    float* out = (float*)d_out;

    const int* src = eidx;
    const int* dst = eidx + NE;

    // workspace: big 16B-aligned arrays first, then the contiguous zeroed
    // region (agg1, agg2, histS, histD, pooled, gcnt), then ints.
    char* base = (char*)d_ws;
    uint32_t* Qp   = (uint32_t*)base;                       // NN*512
    float* ea_p    = (float*)(Qp + (size_t)NN * 512);       // NE*12
    float* Qb      = ea_p + (size_t)NE * 12;                // NN*32
    float* h1      = Qb + (size_t)NN * 32;                  // NN*32
    float* agg1    = h1 + (size_t)NN * 32;                  // NN*32 (zeroed from here)
    float* agg2    = agg1 + (size_t)NN * 32;                // NN*32
    int*   histS   = (int*)(agg2 + (size_t)NN * 32);        // NN
    int*   histD   = histS + NN;                            // NN
    float* pooled  = (float*)(histD + NN);                  // NG*32
    float* gcnt    = pooled + NG * 32;                      // NG
    size_t zero_bytes = ((size_t)NN * 64 + NN * 2 + NG * 32 + NG) * 4;
    int*   src_s   = (int*)(gcnt + NG);                     // NE
    int*   dst_s   = src_s + NE;                            // NE
    int*   rowS    = dst_s + NE;                            // NN+1
    int*   curS    = rowS + NN + 1;                         // NN

    hipMemsetAsync(agg1, 0, zero_bytes, stream);

    // ---- edge sort pre-pass (shared by both convs) ----
    edge_stats_kernel<<<(NE + 255) / 256, 256, 0, stream>>>(src, dst, histS, histD);
    scan_kernel<<<1, 1024, 0, stream>>>(histS, rowS, curS);
    scatter_kernel<<<(NE + 255) / 256, 256, 0, stream>>>(ea, src, dst, curS,
                                                         ea_p, src_s, dst_s);

    const int edge_grid = (NE + EPB - 1) / EPB;
    dim3 qgrid(NN / NCH, 2);

    // ---- conv1 ----
    computeQ_pack_kernel<FEAT><<<qgrid, 256, 0, stream>>>(x, nn1_w2, nn1_b2, Qp, Qb);
    edge_agg_kernel<<<edge_grid, 256, 0, stream>>>(ea_p, src_s, dst_s,
                                                   nn1_w1, nn1_b1, Qp, Qb, agg1);

    // ---- node1 + conv2 Q (fused; replaces node_update1 + computeQ2) ----
    computeQ2h_kernel<<<qgrid, 256, 0, stream>>>(
        agg1, histD, x, root1, bias1, nn2_w2, nn2_b2, h1, Qp, Qb);

    // ---- conv2 ----
    edge_agg_kernel<<<edge_grid, 256, 0, stream>>>(ea_p, src_s, dst_s,
                                                   nn2_w1, nn2_b1, Qp, Qb, agg2);

    // ---- node2 + pooling (computeQ-shaped; replaces node_update2) ----
    pool_kernel<<<NN / NCH, 256, 0, stream>>>(
        agg2, histD, h1, root2, bias2, batch, pooled, gcnt);

    // ---- head ----
    final_kernel<<<1, 64, 0, stream>>>(pooled, gcnt, lin_w, lin_b, out);
}